// Round 1
// baseline (48347.208 us; speedup 1.0000x reference)
//
#include <hip/hip_runtime.h>
#include <hip/hip_bf16.h>
#include <stdint.h>

// Problem constants
#define TT 256
#define BB 64
#define DIN 512
#define RR 2048
#define DOUT 128
#define NTOT (RR*RR)                // 4194304
#define NKEEP 838860                // int(4194304 * (1.0 - 0.8)) in IEEE double
#define BETA 0.9f
#define VTH 1.0f

// ---------------- workspace layout (bytes) ----------------
// drive : float [16384][2048]          @ 0            (134217728 B)
// mask  : u32   [256][64][64]          @ 134217728    (4194304 B)  spike bitmask per t
// ctr   : u32   [256][4]               @ +4MB         (4096 B)     per (t, group) arrival counters
// hist  : u32   [256]
// state : u32   [8]   (0: prefix, 1: remaining, 2: thresh bits)
// cnts  : u32   [2]   (0: spike count, 1: active count)

// ---------------- init: zero mask/ctr/hist/state/cnts ----------------
__global__ void k_init(uint32_t* __restrict__ p, int n) {
    int i = blockIdx.x * blockDim.x + threadIdx.x;
    int stride = gridDim.x * blockDim.x;
    for (; i < n; i += stride) p[i] = 0u;
}

// ---------------- radix select (4 passes x 8 bits, k-th largest) ----------------
__global__ void k_hist(const float* __restrict__ w_rec, uint32_t* __restrict__ hist,
                       const uint32_t* __restrict__ state, int p) {
    __shared__ uint32_t lh[256];
    lh[threadIdx.x] = 0u;
    __syncthreads();
    uint32_t prefix = (p > 0) ? state[0] : 0u;
    int sh = 24 - 8 * p;
    int i = blockIdx.x * 256 + threadIdx.x;
    int stride = gridDim.x * 256;
    for (; i < NTOT; i += stride) {
        uint32_t u = __float_as_uint(fabsf(w_rec[i]));
        bool ok = (p == 0) || ((u >> (sh + 8)) == prefix);
        if (ok) atomicAdd(&lh[(u >> sh) & 255u], 1u);
    }
    __syncthreads();
    uint32_t v = lh[threadIdx.x];
    if (v) atomicAdd(&hist[threadIdx.x], v);
}

__global__ void k_select(uint32_t* __restrict__ hist, uint32_t* __restrict__ state, int p) {
    __shared__ uint32_t lh[256];
    int tid = threadIdx.x;
    lh[tid] = hist[tid];
    hist[tid] = 0u;            // ready for next pass
    __syncthreads();
    if (tid == 0) {
        uint32_t remaining = (p == 0) ? (uint32_t)NKEEP : state[1];
        int bin = 255;
        for (; bin > 0; --bin) {
            uint32_t c = lh[bin];
            if (c >= remaining) break;
            remaining -= c;
        }
        uint32_t pref = (p == 0) ? 0u : state[0];
        pref = (pref << 8) | (uint32_t)bin;
        state[0] = pref;
        state[1] = remaining;
        if (p == 3) state[2] = pref;   // full 32-bit pattern of threshold value
    }
}

__global__ void k_count(const float* __restrict__ w_rec, const uint32_t* __restrict__ state,
                        uint32_t* __restrict__ cnts) {
    uint32_t th = state[2];
    uint32_t c = 0;
    int i = blockIdx.x * 256 + threadIdx.x;
    int stride = gridDim.x * 256;
    for (; i < NTOT; i += stride)
        c += (__float_as_uint(fabsf(w_rec[i])) >= th) ? 1u : 0u;
    // wave reduce (wave64)
    for (int off = 32; off > 0; off >>= 1) c += __shfl_down(c, off);
    if ((threadIdx.x & 63) == 0 && c) atomicAdd(&cnts[1], c);
}

// ---------------- drive GEMM: [16384,512] x [512,2048] + b_in ----------------
__global__ __launch_bounds__(256) void k_drive(const float* __restrict__ x,
                                               const float* __restrict__ w_in,
                                               const float* __restrict__ b_in,
                                               float* __restrict__ drive) {
    __shared__ float As[8][128];
    __shared__ float Bs[8][128];
    const int m0 = blockIdx.x * 128;
    const int n0 = blockIdx.y * 128;
    const int tid = threadIdx.x;
    const int tx = tid & 15, ty = tid >> 4;
    const int ar = tid >> 1;
    const int ak = (tid & 1) * 4;
    const int bk = tid >> 5;
    const int bc = (tid & 31) * 4;
    float acc[8][8];
    #pragma unroll
    for (int i = 0; i < 8; ++i)
        #pragma unroll
        for (int j = 0; j < 8; ++j) acc[i][j] = 0.0f;

    for (int k0 = 0; k0 < DIN; k0 += 8) {
        float4 av = *(const float4*)&x[(m0 + ar) * DIN + k0 + ak];
        float4 bv = *(const float4*)&w_in[(size_t)(k0 + bk) * RR + n0 + bc];
        __syncthreads();
        As[ak + 0][ar] = av.x; As[ak + 1][ar] = av.y;
        As[ak + 2][ar] = av.z; As[ak + 3][ar] = av.w;
        *(float4*)&Bs[bk][bc] = bv;
        __syncthreads();
        #pragma unroll
        for (int kk = 0; kk < 8; ++kk) {
            float a[8], b[8];
            *(float4*)&a[0] = *(const float4*)&As[kk][ty * 8];
            *(float4*)&a[4] = *(const float4*)&As[kk][ty * 8 + 4];
            *(float4*)&b[0] = *(const float4*)&Bs[kk][tx * 8];
            *(float4*)&b[4] = *(const float4*)&Bs[kk][tx * 8 + 4];
            #pragma unroll
            for (int i = 0; i < 8; ++i)
                #pragma unroll
                for (int j = 0; j < 8; ++j)
                    acc[i][j] = fmaf(a[i], b[j], acc[i][j]);
        }
    }
    float bb[8];
    #pragma unroll
    for (int j = 0; j < 8; ++j) bb[j] = b_in[n0 + tx * 8 + j];
    #pragma unroll
    for (int i = 0; i < 8; ++i) {
        size_t row = (size_t)(m0 + ty * 8 + i) * RR + n0 + tx * 8;
        float4 v0, v1;
        v0.x = acc[i][0] + bb[0]; v0.y = acc[i][1] + bb[1];
        v0.z = acc[i][2] + bb[2]; v0.w = acc[i][3] + bb[3];
        v1.x = acc[i][4] + bb[4]; v1.y = acc[i][5] + bb[5];
        v1.z = acc[i][6] + bb[6]; v1.w = acc[i][7] + bb[7];
        *(float4*)&drive[row] = v0;
        *(float4*)&drive[row + 4] = v1;
    }
}

// ---------------- recurrent scan ----------------
// 512 blocks x 256 threads. Block owns 4 columns (col0 = blk*4), LDS-resident w_eff chunk.
// 4 batch-groups of 16 batches; wave g = group g. Per-group atomic barrier per timestep.
__global__ __launch_bounds__(256) void k_scan(const float* __restrict__ w_rec,
                                              const float* __restrict__ drive,
                                              uint32_t* mask, uint32_t* ctr,
                                              const uint32_t* __restrict__ state,
                                              uint32_t* cnts) {
    __shared__ float wch[RR * 4];            // [2048][4] masked w_rec columns, 32 KB
    __shared__ uint32_t mb[4 * 16 * 65];     // per-group staged spike masks, padded rows

    const int tid = threadIdx.x;
    const int blk = blockIdx.x;              // 0..511
    const int col0 = blk * 4;
    const float thresh = __uint_as_float(state[2]);

    for (int idx = tid; idx < RR * 4; idx += 256) {
        int i = idx >> 2, c = idx & 3;
        float v = w_rec[(size_t)i * RR + col0 + c];
        wch[idx] = (fabsf(v) >= thresh) ? v : 0.0f;
    }
    __syncthreads();

    const int g = tid >> 6;        // wave id == batch group
    const int lane = tid & 63;
    const int bl = lane >> 2;      // 0..15 batch-in-group
    const int c = lane & 3;        // column-in-block
    const int b = g * 16 + bl;
    uint32_t* mbg = &mb[g * 16 * 65];

    float V = 0.0f;
    uint32_t scnt = 0;

    for (int t = 0; t < TT; ++t) {
        if (t > 0) {
            if (lane == 0) {
                while (__hip_atomic_load(&ctr[(t - 1) * 4 + g], __ATOMIC_ACQUIRE,
                                         __HIP_MEMORY_SCOPE_AGENT) < 512u)
                    __builtin_amdgcn_s_sleep(2);
            }
            __builtin_amdgcn_wave_barrier();
            // stage this group's 1024 mask words (16 batches x 64 words)
            const uint32_t* gsrc = &mask[(t - 1) * 4096 + g * 1024];
            #pragma unroll
            for (int q = 0; q < 16; ++q) {
                int idx = q * 64 + lane;
                uint32_t w = __hip_atomic_load(&gsrc[idx], __ATOMIC_RELAXED,
                                               __HIP_MEMORY_SCOPE_AGENT);
                mbg[(idx >> 6) * 65 + (idx & 63)] = w;
            }
            __builtin_amdgcn_wave_barrier();
        }

        float acc = drive[(size_t)t * (BB * RR) + b * RR + col0 + c];
        if (t > 0) {
            const uint32_t* mrow = &mbg[bl * 65];
            for (int w = 0; w < 64; ++w) {
                uint32_t m = mrow[w];
                int base = w << 5;
                while (m) {
                    int bit = __builtin_ctz(m);
                    m &= m - 1;
                    acc += wch[((base + bit) << 2) + c];
                }
            }
        }

        V = BETA * V + acc;
        bool sp = V > VTH;
        if (sp) V -= VTH;

        unsigned long long bal = __ballot(sp ? 1 : 0);
        if (c == 0) {
            uint32_t nib = (uint32_t)(bal >> (bl * 4)) & 0xFu;
            if (nib)
                atomicOr(&mask[t * 4096 + b * 64 + (blk >> 3)], nib << ((blk & 7) * 4));
        }
        if (lane == 0) scnt += (uint32_t)__popcll(bal);

        __threadfence();   // make spike writes agent-visible before arrival
        if (lane == 0)
            __hip_atomic_fetch_add(&ctr[t * 4 + g], 1u, __ATOMIC_RELEASE,
                                   __HIP_MEMORY_SCOPE_AGENT);
    }
    if (lane == 0 && scnt) atomicAdd(&cnts[0], scnt);
}

// ---------------- head: logits[t,b,:] = s @ w_head + b_head (sparse gather) ----------------
__global__ __launch_bounds__(128) void k_head(const uint32_t* __restrict__ mask,
                                              const float* __restrict__ w_head,
                                              const float* __restrict__ b_head,
                                              float* __restrict__ logits) {
    __shared__ uint32_t sm[64];
    int tb = blockIdx.x;        // t*64 + b
    int tid = threadIdx.x;      // 0..127
    if (tid < 64) sm[tid] = mask[tb * 64 + tid];
    __syncthreads();
    float acc = b_head[tid];
    for (int w = 0; w < 64; ++w) {
        uint32_t m = sm[w];     // uniform per block -> no divergence
        int base = w << 5;
        while (m) {
            int bit = __builtin_ctz(m);
            m &= m - 1;
            acc += w_head[(size_t)(base + bit) * DOUT + tid];
        }
    }
    logits[(size_t)tb * DOUT + tid] = acc;
}

// ---------------- readout: mean over T ----------------
__global__ __launch_bounds__(128) void k_readout(const float* __restrict__ logits,
                                                 float* __restrict__ readout) {
    int b = blockIdx.x, cidx = threadIdx.x;
    float s = 0.0f;
    for (int t = 0; t < TT; ++t)
        s += logits[(size_t)t * (BB * DOUT) + b * DOUT + cidx];
    readout[b * DOUT + cidx] = s * (1.0f / (float)TT);
}

// ---------------- scalars ----------------
__global__ void k_scalars(const uint32_t* __restrict__ cnts, float* __restrict__ out) {
    if (threadIdx.x == 0 && blockIdx.x == 0) {
        out[BB * DOUT + TT * BB * DOUT]     = (float)cnts[0] / (float)(TT * BB * RR);
        out[BB * DOUT + TT * BB * DOUT + 1] = (float)cnts[1] / (float)NTOT;
    }
}

extern "C" void kernel_launch(void* const* d_in, const int* in_sizes, int n_in,
                              void* d_out, int out_size, void* d_ws, size_t ws_size,
                              hipStream_t stream) {
    const float* x      = (const float*)d_in[0];
    const float* w_in   = (const float*)d_in[1];
    const float* b_in   = (const float*)d_in[2];
    const float* w_rec  = (const float*)d_in[3];
    const float* w_head = (const float*)d_in[4];
    const float* b_head = (const float*)d_in[5];
    float* out = (float*)d_out;

    float*    drive = (float*)d_ws;
    uint32_t* mask  = (uint32_t*)((char*)d_ws + 134217728u);
    uint32_t* ctr   = mask + 1048576;
    uint32_t* hist  = ctr + 1024;
    uint32_t* state = hist + 256;
    uint32_t* cnts  = state + 8;

    // zero mask + ctr + hist + state + cnts (contiguous)
    k_init<<<1024, 256, 0, stream>>>(mask, 1048576 + 1024 + 256 + 8 + 2);

    for (int p = 0; p < 4; ++p) {
        k_hist<<<1024, 256, 0, stream>>>(w_rec, hist, state, p);
        k_select<<<1, 256, 0, stream>>>(hist, state, p);
    }
    k_count<<<1024, 256, 0, stream>>>(w_rec, state, cnts);

    k_drive<<<dim3(128, 16), 256, 0, stream>>>(x, w_in, b_in, drive);

    k_scan<<<512, 256, 0, stream>>>(w_rec, drive, mask, ctr, state, cnts);

    k_head<<<TT * BB, 128, 0, stream>>>(mask, w_head, b_head, out + BB * DOUT);
    k_readout<<<BB, 128, 0, stream>>>(out + BB * DOUT, out);
    k_scalars<<<1, 64, 0, stream>>>(cnts, out);
}

// Round 3
// 8967.799 us; speedup vs baseline: 5.3912x; 5.3912x over previous
//
#include <hip/hip_runtime.h>
#include <hip/hip_bf16.h>
#include <stdint.h>

// Problem constants
#define TT 256
#define BB 64
#define DIN 512
#define RR 2048
#define DOUT 128
#define NTOT (RR*RR)                // 4194304
#define NKEEP 838860                // int(4194304 * (1.0 - 0.8)) in IEEE double
#define BETA 0.9f
#define VTH 1.0f

// ---------------- workspace layout (bytes) ----------------
// drive : float [16384][2048]   @ 0            (134217728 B)
// mask  : u32   [256][64][64]   @ 134217728    (4194304 B)   spike bitmask per (t,b)
// ctr   : u32   [256][64]       @ +4MB         (65536 B)     per (t,batch) arrival counters
// hist  : u32   [256]
// state : u32   [8]   (0: prefix, 1: remaining, 2: thresh bits)
// cnts  : u32   [2]   (0: spike count, 1: active count)

__global__ void k_init(uint32_t* __restrict__ p, int n) {
    int i = blockIdx.x * blockDim.x + threadIdx.x;
    int stride = gridDim.x * blockDim.x;
    for (; i < n; i += stride) p[i] = 0u;
}

// ---------------- radix select (4 passes x 8 bits, k-th largest) ----------------
__global__ void k_hist(const float* __restrict__ w_rec, uint32_t* __restrict__ hist,
                       const uint32_t* __restrict__ state, int p) {
    __shared__ uint32_t lh[256];
    lh[threadIdx.x] = 0u;
    __syncthreads();
    uint32_t prefix = (p > 0) ? state[0] : 0u;
    int sh = 24 - 8 * p;
    int i = blockIdx.x * 256 + threadIdx.x;
    int stride = gridDim.x * 256;
    for (; i < NTOT; i += stride) {
        uint32_t u = __float_as_uint(fabsf(w_rec[i]));
        bool ok = (p == 0) || ((u >> (sh + 8)) == prefix);
        if (ok) atomicAdd(&lh[(u >> sh) & 255u], 1u);
    }
    __syncthreads();
    uint32_t v = lh[threadIdx.x];
    if (v) atomicAdd(&hist[threadIdx.x], v);
}

__global__ void k_select(uint32_t* __restrict__ hist, uint32_t* __restrict__ state, int p) {
    __shared__ uint32_t lh[256];
    int tid = threadIdx.x;
    lh[tid] = hist[tid];
    hist[tid] = 0u;            // ready for next pass
    __syncthreads();
    if (tid == 0) {
        uint32_t remaining = (p == 0) ? (uint32_t)NKEEP : state[1];
        int bin = 255;
        for (; bin > 0; --bin) {
            uint32_t c = lh[bin];
            if (c >= remaining) break;
            remaining -= c;
        }
        uint32_t pref = (p == 0) ? 0u : state[0];
        pref = (pref << 8) | (uint32_t)bin;
        state[0] = pref;
        state[1] = remaining;
        if (p == 3) state[2] = pref;   // full 32-bit pattern of threshold value
    }
}

__global__ void k_count(const float* __restrict__ w_rec, const uint32_t* __restrict__ state,
                        uint32_t* __restrict__ cnts) {
    uint32_t th = state[2];
    uint32_t c = 0;
    int i = blockIdx.x * 256 + threadIdx.x;
    int stride = gridDim.x * 256;
    for (; i < NTOT; i += stride)
        c += (__float_as_uint(fabsf(w_rec[i])) >= th) ? 1u : 0u;
    for (int off = 32; off > 0; off >>= 1) c += __shfl_down(c, off);
    if ((threadIdx.x & 63) == 0 && c) atomicAdd(&cnts[1], c);
}

// ---------------- drive GEMM: [16384,512] x [512,2048] + b_in ----------------
__global__ __launch_bounds__(256) void k_drive(const float* __restrict__ x,
                                               const float* __restrict__ w_in,
                                               const float* __restrict__ b_in,
                                               float* __restrict__ drive) {
    __shared__ float As[8][128];
    __shared__ float Bs[8][128];
    const int m0 = blockIdx.x * 128;
    const int n0 = blockIdx.y * 128;
    const int tid = threadIdx.x;
    const int tx = tid & 15, ty = tid >> 4;
    const int ar = tid >> 1;
    const int ak = (tid & 1) * 4;
    const int bk = tid >> 5;
    const int bc = (tid & 31) * 4;
    float acc[8][8];
    #pragma unroll
    for (int i = 0; i < 8; ++i)
        #pragma unroll
        for (int j = 0; j < 8; ++j) acc[i][j] = 0.0f;

    for (int k0 = 0; k0 < DIN; k0 += 8) {
        float4 av = *(const float4*)&x[(m0 + ar) * DIN + k0 + ak];
        float4 bv = *(const float4*)&w_in[(size_t)(k0 + bk) * RR + n0 + bc];
        __syncthreads();
        As[ak + 0][ar] = av.x; As[ak + 1][ar] = av.y;
        As[ak + 2][ar] = av.z; As[ak + 3][ar] = av.w;
        *(float4*)&Bs[bk][bc] = bv;
        __syncthreads();
        #pragma unroll
        for (int kk = 0; kk < 8; ++kk) {
            float a[8], b[8];
            *(float4*)&a[0] = *(const float4*)&As[kk][ty * 8];
            *(float4*)&a[4] = *(const float4*)&As[kk][ty * 8 + 4];
            *(float4*)&b[0] = *(const float4*)&Bs[kk][tx * 8];
            *(float4*)&b[4] = *(const float4*)&Bs[kk][tx * 8 + 4];
            #pragma unroll
            for (int i = 0; i < 8; ++i)
                #pragma unroll
                for (int j = 0; j < 8; ++j)
                    acc[i][j] = fmaf(a[i], b[j], acc[i][j]);
        }
    }
    float bb[8];
    #pragma unroll
    for (int j = 0; j < 8; ++j) bb[j] = b_in[n0 + tx * 8 + j];
    #pragma unroll
    for (int i = 0; i < 8; ++i) {
        size_t row = (size_t)(m0 + ty * 8 + i) * RR + n0 + tx * 8;
        float4 v0, v1;
        v0.x = acc[i][0] + bb[0]; v0.y = acc[i][1] + bb[1];
        v0.z = acc[i][2] + bb[2]; v0.w = acc[i][3] + bb[3];
        v1.x = acc[i][4] + bb[4]; v1.y = acc[i][5] + bb[5];
        v1.z = acc[i][6] + bb[6]; v1.w = acc[i][7] + bb[7];
        *(float4*)&drive[row] = v0;
        *(float4*)&drive[row + 4] = v1;
    }
}

// ---------------- recurrent scan: 256 blocks = 64 batches x 4 column-slices ----------------
// Block handles one batch's 512-column slice. Spike exchange within the 4-block group
// via per-(t,batch) counters. Spike list built once per step (uniform for all threads);
// gather is coalesced float2 row reads, fixed ascending accumulation order.
// NUMERICS: accumulator STARTS at the drive value and V = BETA*V + acc (single fma) --
// bit-identical association to the round-1 kernel that passed with zero spike flips.
__global__ __launch_bounds__(256) void k_scan(const float* __restrict__ w_rec,
                                              const float* __restrict__ drive,
                                              uint32_t* mask, uint32_t* ctr,
                                              const uint32_t* __restrict__ state,
                                              uint32_t* cnts) {
    __shared__ int s_list[RR];        // spike row indices (8 KB)
    __shared__ uint32_t s_own[16];    // this slice's 512 spike bits
    __shared__ int s_n;
    __shared__ uint32_t s_red[4];

    const int tid = threadIdx.x;
    const int blk = blockIdx.x;       // 0..255
    const int x = blk & 7;            // heuristic XCD id
    const int q = blk >> 3;
    const int slice = x & 3;          // same slice stays on same XCD pair -> L2 locality
    const int b = 2 * q + (x >> 2);   // batch 0..63
    const int c0 = slice * 512 + 2 * tid;   // absolute first column of this thread's pair
    const float th = __uint_as_float(state[2]);

    float V0 = 0.f, V1 = 0.f;
    uint32_t scnt = 0;
    float2 dv = *(const float2*)&drive[(size_t)b * RR + c0];   // t = 0

    for (int t = 0; t < TT; ++t) {
        float a0 = dv.x, a1 = dv.y;   // start from drive (round-1 summation order)
        if (t > 0) {
            if (tid == 0) {
                while (__hip_atomic_load(&ctr[(t - 1) * BB + b], __ATOMIC_ACQUIRE,
                                         __HIP_MEMORY_SCOPE_AGENT) < 4u)
                    __builtin_amdgcn_s_sleep(1);
            }
            __syncthreads();
            if (tid < 64) {   // wave 0: load batch mask, build ascending spike list
                uint32_t m = __hip_atomic_load(&mask[((size_t)(t - 1) * BB + b) * 64 + tid],
                                               __ATOMIC_RELAXED, __HIP_MEMORY_SCOPE_AGENT);
                int p = __popc(m);
                int off = p;
                #pragma unroll
                for (int d = 1; d < 64; d <<= 1) {
                    int o = __shfl_up(off, d);
                    if (tid >= d) off += o;
                }
                int e = off - p;
                if (tid == 63) s_n = off;
                int base = tid << 5;
                while (m) { int bit = __builtin_ctz(m); m &= m - 1; s_list[e++] = base + bit; }
            }
            __syncthreads();
            const int n = s_n;
            const float* Wp = w_rec + c0;
            int i = 0;
            for (; i + 4 <= n; i += 4) {
                int r0 = s_list[i], r1 = s_list[i + 1], r2 = s_list[i + 2], r3 = s_list[i + 3];
                float2 v0 = *(const float2*)(Wp + (size_t)r0 * RR);
                float2 v1 = *(const float2*)(Wp + (size_t)r1 * RR);
                float2 v2 = *(const float2*)(Wp + (size_t)r2 * RR);
                float2 v3 = *(const float2*)(Wp + (size_t)r3 * RR);
                a0 += (fabsf(v0.x) >= th) ? v0.x : 0.f;
                a1 += (fabsf(v0.y) >= th) ? v0.y : 0.f;
                a0 += (fabsf(v1.x) >= th) ? v1.x : 0.f;
                a1 += (fabsf(v1.y) >= th) ? v1.y : 0.f;
                a0 += (fabsf(v2.x) >= th) ? v2.x : 0.f;
                a1 += (fabsf(v2.y) >= th) ? v2.y : 0.f;
                a0 += (fabsf(v3.x) >= th) ? v3.x : 0.f;
                a1 += (fabsf(v3.y) >= th) ? v3.y : 0.f;
            }
            for (; i < n; ++i) {
                int r = s_list[i];
                float2 v = *(const float2*)(Wp + (size_t)r * RR);
                a0 += (fabsf(v.x) >= th) ? v.x : 0.f;
                a1 += (fabsf(v.y) >= th) ? v.y : 0.f;
            }
        }

        V0 = BETA * V0 + a0;    // fma(BETA, V0, drive + sum) -- round-1 contraction
        V1 = BETA * V1 + a1;
        bool sp0 = V0 > VTH, sp1 = V1 > VTH;
        if (sp0) V0 -= VTH;
        if (sp1) V1 -= VTH;
        scnt += (sp0 ? 1u : 0u) + (sp1 ? 1u : 0u);

        if (t + 1 < TT)   // prefetch next drive before the exchange (independent of spikes)
            dv = *(const float2*)&drive[((size_t)(t + 1) * BB + b) * RR + c0];

        if (tid < 16) s_own[tid] = 0u;
        __syncthreads();
        uint32_t bits = (sp0 ? 1u : 0u) | (sp1 ? 2u : 0u);
        if (bits) atomicOr(&s_own[tid >> 4], bits << ((tid & 15) * 2));
        __syncthreads();
        if (tid < 16)
            __hip_atomic_store(&mask[((size_t)t * BB + b) * 64 + slice * 16 + tid],
                               s_own[tid], __ATOMIC_RELAXED, __HIP_MEMORY_SCOPE_AGENT);
        __threadfence();
        __syncthreads();
        if (tid == 0)
            __hip_atomic_fetch_add(&ctr[t * BB + b], 1u, __ATOMIC_RELEASE,
                                   __HIP_MEMORY_SCOPE_AGENT);
    }

    for (int off = 32; off > 0; off >>= 1) scnt += __shfl_down(scnt, off);
    if ((tid & 63) == 0) s_red[tid >> 6] = scnt;
    __syncthreads();
    if (tid == 0) {
        uint32_t s = s_red[0] + s_red[1] + s_red[2] + s_red[3];
        if (s) atomicAdd(&cnts[0], s);
    }
}

// ---------------- head: logits[t,b,:] = s @ w_head + b_head (sparse gather) ----------------
__global__ __launch_bounds__(128) void k_head(const uint32_t* __restrict__ mask,
                                              const float* __restrict__ w_head,
                                              const float* __restrict__ b_head,
                                              float* __restrict__ logits) {
    __shared__ uint32_t sm[64];
    int tb = blockIdx.x;        // t*64 + b
    int tid = threadIdx.x;      // 0..127
    if (tid < 64) sm[tid] = mask[tb * 64 + tid];
    __syncthreads();
    float acc = b_head[tid];
    for (int w = 0; w < 64; ++w) {
        uint32_t m = sm[w];     // uniform per block -> no divergence
        int base = w << 5;
        while (m) {
            int bit = __builtin_ctz(m);
            m &= m - 1;
            acc += w_head[(size_t)(base + bit) * DOUT + tid];
        }
    }
    logits[(size_t)tb * DOUT + tid] = acc;
}

__global__ __launch_bounds__(128) void k_readout(const float* __restrict__ logits,
                                                 float* __restrict__ readout) {
    int b = blockIdx.x, cidx = threadIdx.x;
    float s = 0.0f;
    for (int t = 0; t < TT; ++t)
        s += logits[(size_t)t * (BB * DOUT) + b * DOUT + cidx];
    readout[b * DOUT + cidx] = s * (1.0f / (float)TT);
}

__global__ void k_scalars(const uint32_t* __restrict__ cnts, float* __restrict__ out) {
    if (threadIdx.x == 0 && blockIdx.x == 0) {
        out[BB * DOUT + TT * BB * DOUT]     = (float)cnts[0] / (float)(TT * BB * RR);
        out[BB * DOUT + TT * BB * DOUT + 1] = (float)cnts[1] / (float)NTOT;
    }
}

extern "C" void kernel_launch(void* const* d_in, const int* in_sizes, int n_in,
                              void* d_out, int out_size, void* d_ws, size_t ws_size,
                              hipStream_t stream) {
    const float* x      = (const float*)d_in[0];
    const float* w_in   = (const float*)d_in[1];
    const float* b_in   = (const float*)d_in[2];
    const float* w_rec  = (const float*)d_in[3];
    const float* w_head = (const float*)d_in[4];
    const float* b_head = (const float*)d_in[5];
    float* out = (float*)d_out;

    float*    drive = (float*)d_ws;
    uint32_t* mask  = (uint32_t*)((char*)d_ws + 134217728u);
    uint32_t* ctr   = mask + (TT * BB * 64);   // 4 MB of mask words
    uint32_t* hist  = ctr + (TT * BB);
    uint32_t* state = hist + 256;
    uint32_t* cnts  = state + 8;

    // zero ctr + hist + state + cnts (mask words are fully overwritten each step)
    k_init<<<64, 256, 0, stream>>>(ctr, TT * BB + 256 + 8 + 2);

    for (int p = 0; p < 4; ++p) {
        k_hist<<<1024, 256, 0, stream>>>(w_rec, hist, state, p);
        k_select<<<1, 256, 0, stream>>>(hist, state, p);
    }
    k_count<<<1024, 256, 0, stream>>>(w_rec, state, cnts);

    k_drive<<<dim3(128, 16), 256, 0, stream>>>(x, w_in, b_in, drive);

    k_scan<<<256, 256, 0, stream>>>(w_rec, drive, mask, ctr, state, cnts);

    k_head<<<TT * BB, 128, 0, stream>>>(mask, w_head, b_head, out + BB * DOUT);
    k_readout<<<BB, 128, 0, stream>>>(out + BB * DOUT, out);
    k_scalars<<<1, 64, 0, stream>>>(cnts, out);
}

// Round 4
// 5655.914 us; speedup vs baseline: 8.5481x; 1.5856x over previous
//
#include <hip/hip_runtime.h>
#include <hip/hip_bf16.h>
#include <stdint.h>

// Problem constants
#define TT 256
#define BB 64
#define DIN 512
#define RR 2048
#define DOUT 128
#define NTOT (RR*RR)                // 4194304
#define NKEEP 838860                // int(4194304 * (1.0 - 0.8)) in IEEE double
#define BETA 0.9f
#define VTH 1.0f

// ---------------- workspace layout ----------------
// drive : float [16384][2048]   @ 0            (134217728 B)
// mask  : u32   [256][64][64]   @ 134217728    (4194304 B)   spike bitmask per (t,b)
// ctr   : u32   [256][64]       @ +4MB         per (t,batch) arrival counters
// hist  : u32   [256]
// state : u32   [8]   (0: prefix, 1: remaining, 2: thresh bits)
// cnts  : u32   [2]   (0: spike count, 1: active count)
// NOTE: w_rec is masked IN PLACE (harness restores pristine inputs before every launch).

__global__ void k_init(uint32_t* __restrict__ p, int n) {
    int i = blockIdx.x * blockDim.x + threadIdx.x;
    int stride = gridDim.x * blockDim.x;
    for (; i < n; i += stride) p[i] = 0u;
}

// ---------------- radix select (4 passes x 8 bits, k-th largest) ----------------
__global__ void k_hist(const float* __restrict__ w_rec, uint32_t* __restrict__ hist,
                       const uint32_t* __restrict__ state, int p) {
    __shared__ uint32_t lh[256];
    lh[threadIdx.x] = 0u;
    __syncthreads();
    uint32_t prefix = (p > 0) ? state[0] : 0u;
    int sh = 24 - 8 * p;
    int i = blockIdx.x * 256 + threadIdx.x;
    int stride = gridDim.x * 256;
    for (; i < NTOT; i += stride) {
        uint32_t u = __float_as_uint(fabsf(w_rec[i]));
        bool ok = (p == 0) || ((u >> (sh + 8)) == prefix);
        if (ok) atomicAdd(&lh[(u >> sh) & 255u], 1u);
    }
    __syncthreads();
    uint32_t v = lh[threadIdx.x];
    if (v) atomicAdd(&hist[threadIdx.x], v);
}

__global__ void k_select(uint32_t* __restrict__ hist, uint32_t* __restrict__ state, int p) {
    __shared__ uint32_t lh[256];
    int tid = threadIdx.x;
    lh[tid] = hist[tid];
    hist[tid] = 0u;            // ready for next pass
    __syncthreads();
    if (tid == 0) {
        uint32_t remaining = (p == 0) ? (uint32_t)NKEEP : state[1];
        int bin = 255;
        for (; bin > 0; --bin) {
            uint32_t c = lh[bin];
            if (c >= remaining) break;
            remaining -= c;
        }
        uint32_t pref = (p == 0) ? 0u : state[0];
        pref = (pref << 8) | (uint32_t)bin;
        state[0] = pref;
        state[1] = remaining;
        if (p == 3) state[2] = pref;   // full 32-bit pattern of threshold value
    }
}

__global__ void k_count(const float* __restrict__ w_rec, const uint32_t* __restrict__ state,
                        uint32_t* __restrict__ cnts) {
    uint32_t th = state[2];
    uint32_t c = 0;
    int i = blockIdx.x * 256 + threadIdx.x;
    int stride = gridDim.x * 256;
    for (; i < NTOT; i += stride)
        c += (__float_as_uint(fabsf(w_rec[i])) >= th) ? 1u : 0u;
    for (int off = 32; off > 0; off >>= 1) c += __shfl_down(c, off);
    if ((threadIdx.x & 63) == 0 && c) atomicAdd(&cnts[1], c);
}

// ---------------- mask w_rec in place: w = |w|>=th ? w : 0 ----------------
// Adding stored 0.0f is bit-identical to the previous cndmask +0.0f path.
__global__ void k_mask(float* __restrict__ w, const uint32_t* __restrict__ state) {
    uint32_t th = state[2];
    int i = blockIdx.x * blockDim.x + threadIdx.x;       // float4 index
    int stride = gridDim.x * blockDim.x;
    for (; i < NTOT / 4; i += stride) {
        float4 v = *(float4*)&w[i * 4];
        if ((__float_as_uint(v.x) & 0x7fffffffu) < th) v.x = 0.0f;
        if ((__float_as_uint(v.y) & 0x7fffffffu) < th) v.y = 0.0f;
        if ((__float_as_uint(v.z) & 0x7fffffffu) < th) v.z = 0.0f;
        if ((__float_as_uint(v.w) & 0x7fffffffu) < th) v.w = 0.0f;
        *(float4*)&w[i * 4] = v;
    }
}

// ---------------- drive GEMM: [16384,512] x [512,2048] + b_in ----------------
__global__ __launch_bounds__(256) void k_drive(const float* __restrict__ x,
                                               const float* __restrict__ w_in,
                                               const float* __restrict__ b_in,
                                               float* __restrict__ drive) {
    __shared__ float As[8][128];
    __shared__ float Bs[8][128];
    const int m0 = blockIdx.x * 128;
    const int n0 = blockIdx.y * 128;
    const int tid = threadIdx.x;
    const int tx = tid & 15, ty = tid >> 4;
    const int ar = tid >> 1;
    const int ak = (tid & 1) * 4;
    const int bk = tid >> 5;
    const int bc = (tid & 31) * 4;
    float acc[8][8];
    #pragma unroll
    for (int i = 0; i < 8; ++i)
        #pragma unroll
        for (int j = 0; j < 8; ++j) acc[i][j] = 0.0f;

    for (int k0 = 0; k0 < DIN; k0 += 8) {
        float4 av = *(const float4*)&x[(m0 + ar) * DIN + k0 + ak];
        float4 bv = *(const float4*)&w_in[(size_t)(k0 + bk) * RR + n0 + bc];
        __syncthreads();
        As[ak + 0][ar] = av.x; As[ak + 1][ar] = av.y;
        As[ak + 2][ar] = av.z; As[ak + 3][ar] = av.w;
        *(float4*)&Bs[bk][bc] = bv;
        __syncthreads();
        #pragma unroll
        for (int kk = 0; kk < 8; ++kk) {
            float a[8], b[8];
            *(float4*)&a[0] = *(const float4*)&As[kk][ty * 8];
            *(float4*)&a[4] = *(const float4*)&As[kk][ty * 8 + 4];
            *(float4*)&b[0] = *(const float4*)&Bs[kk][tx * 8];
            *(float4*)&b[4] = *(const float4*)&Bs[kk][tx * 8 + 4];
            #pragma unroll
            for (int i = 0; i < 8; ++i)
                #pragma unroll
                for (int j = 0; j < 8; ++j)
                    acc[i][j] = fmaf(a[i], b[j], acc[i][j]);
        }
    }
    float bb[8];
    #pragma unroll
    for (int j = 0; j < 8; ++j) bb[j] = b_in[n0 + tx * 8 + j];
    #pragma unroll
    for (int i = 0; i < 8; ++i) {
        size_t row = (size_t)(m0 + ty * 8 + i) * RR + n0 + tx * 8;
        float4 v0, v1;
        v0.x = acc[i][0] + bb[0]; v0.y = acc[i][1] + bb[1];
        v0.z = acc[i][2] + bb[2]; v0.w = acc[i][3] + bb[3];
        v1.x = acc[i][4] + bb[4]; v1.y = acc[i][5] + bb[5];
        v1.z = acc[i][6] + bb[6]; v1.w = acc[i][7] + bb[7];
        *(float4*)&drive[row] = v0;
        *(float4*)&drive[row + 4] = v1;
    }
}

__device__ __forceinline__ uint32_t spread16(uint32_t x) {
    x &= 0xFFFFu;
    x = (x | (x << 8)) & 0x00FF00FFu;
    x = (x | (x << 4)) & 0x0F0F0F0Fu;
    x = (x | (x << 2)) & 0x33333333u;
    x = (x | (x << 1)) & 0x55555555u;
    return x;
}

// ---------------- recurrent scan: 256 blocks = 64 batches x 4 column-slices ----------------
// Same arithmetic order as the passing round-3 kernel: acc starts at drive, spike rows
// added in ascending index order, V = fma(BETA, V, acc). w_rec is pre-masked so the
// gather is a pure add chain; 16-row load batches for memory-level parallelism.
__global__ __launch_bounds__(256) void k_scan(const float* __restrict__ w_rec,
                                              const float* __restrict__ drive,
                                              uint32_t* mask, uint32_t* ctr,
                                              uint32_t* cnts) {
    __shared__ int s_list[RR];        // spike row indices (8 KB)
    __shared__ int s_n;
    __shared__ uint32_t s_red[4];

    const int tid = threadIdx.x;
    const int blk = blockIdx.x;       // 0..255
    const int x = blk & 7;            // heuristic XCD id
    const int q = blk >> 3;
    const int slice = x & 3;          // same slice stays on same XCD -> L2 locality
    const int b = 2 * q + (x >> 2);   // batch 0..63
    const int c0 = slice * 512 + 2 * tid;   // first column of this thread's pair
    const int w = tid >> 6;           // wave id
    const int lane = tid & 63;

    float V0 = 0.f, V1 = 0.f;
    uint32_t scnt = 0;
    float2 dv = *(const float2*)&drive[(size_t)b * RR + c0];   // t = 0

    for (int t = 0; t < TT; ++t) {
        float a0 = dv.x, a1 = dv.y;   // start from drive (round-1/3 summation order)
        if (t > 0) {
            if (tid == 0) {
                while (__hip_atomic_load(&ctr[(t - 1) * BB + b], __ATOMIC_ACQUIRE,
                                         __HIP_MEMORY_SCOPE_AGENT) < 4u)
                    __builtin_amdgcn_s_sleep(1);
            }
            __syncthreads();
            if (tid < 64) {   // wave 0: load batch mask, build ascending spike list
                uint32_t m = __hip_atomic_load(&mask[((size_t)(t - 1) * BB + b) * 64 + tid],
                                               __ATOMIC_RELAXED, __HIP_MEMORY_SCOPE_AGENT);
                int p = __popc(m);
                int off = p;
                #pragma unroll
                for (int d = 1; d < 64; d <<= 1) {
                    int o = __shfl_up(off, d);
                    if (tid >= d) off += o;
                }
                int e = off - p;
                if (tid == 63) s_n = off;
                int base = tid << 5;
                while (m) { int bit = __builtin_ctz(m); m &= m - 1; s_list[e++] = base + bit; }
            }
            __syncthreads();
            const int n = s_n;
            const float* Wp = w_rec + c0;
            int i = 0;
            for (; i + 16 <= n; i += 16) {
                float2 v[16];
                #pragma unroll
                for (int j = 0; j < 16; ++j)
                    v[j] = *(const float2*)(Wp + ((size_t)s_list[i + j] << 11));
                #pragma unroll
                for (int j = 0; j < 16; ++j) { a0 += v[j].x; a1 += v[j].y; }
            }
            for (; i + 4 <= n; i += 4) {
                float2 v0 = *(const float2*)(Wp + ((size_t)s_list[i + 0] << 11));
                float2 v1 = *(const float2*)(Wp + ((size_t)s_list[i + 1] << 11));
                float2 v2 = *(const float2*)(Wp + ((size_t)s_list[i + 2] << 11));
                float2 v3 = *(const float2*)(Wp + ((size_t)s_list[i + 3] << 11));
                a0 += v0.x; a1 += v0.y;
                a0 += v1.x; a1 += v1.y;
                a0 += v2.x; a1 += v2.y;
                a0 += v3.x; a1 += v3.y;
            }
            for (; i < n; ++i) {
                float2 v = *(const float2*)(Wp + ((size_t)s_list[i] << 11));
                a0 += v.x; a1 += v.y;
            }
        }

        V0 = BETA * V0 + a0;    // fma(BETA, V0, drive + sum) -- passing contraction
        V1 = BETA * V1 + a1;
        bool sp0 = V0 > VTH, sp1 = V1 > VTH;
        if (sp0) V0 -= VTH;
        if (sp1) V1 -= VTH;

        if (t + 1 < TT)   // prefetch next drive before the exchange
            dv = *(const float2*)&drive[((size_t)(t + 1) * BB + b) * RR + c0];

        // ballot-based spike export: wave w covers within-slice bits [128w, 128w+128)
        unsigned long long bal0 = __ballot(sp0);
        unsigned long long bal1 = __ballot(sp1);
        if (lane < 4) {
            uint32_t lo = (uint32_t)(bal0 >> (16 * lane)) & 0xFFFFu;
            uint32_t hi = (uint32_t)(bal1 >> (16 * lane)) & 0xFFFFu;
            uint32_t word = spread16(lo) | (spread16(hi) << 1);
            __hip_atomic_store(&mask[((size_t)t * BB + b) * 64 + slice * 16 + w * 4 + lane],
                               word, __ATOMIC_RELAXED, __HIP_MEMORY_SCOPE_AGENT);
        }
        if (lane == 0) scnt += (uint32_t)__popcll(bal0) + (uint32_t)__popcll(bal1);

        __syncthreads();   // all waves' mask stores drained (vmcnt(0) before barrier)
        if (tid == 0) {
            __threadfence();
            __hip_atomic_fetch_add(&ctr[t * BB + b], 1u, __ATOMIC_RELEASE,
                                   __HIP_MEMORY_SCOPE_AGENT);
        }
    }

    if (lane == 0) s_red[w] = scnt;
    __syncthreads();
    if (tid == 0) {
        uint32_t s = s_red[0] + s_red[1] + s_red[2] + s_red[3];
        if (s) atomicAdd(&cnts[0], s);
    }
}

// ---------------- head: logits[t,b,:] = s @ w_head + b_head (sparse gather) ----------------
__global__ __launch_bounds__(128) void k_head(const uint32_t* __restrict__ mask,
                                              const float* __restrict__ w_head,
                                              const float* __restrict__ b_head,
                                              float* __restrict__ logits) {
    __shared__ uint32_t sm[64];
    int tb = blockIdx.x;        // t*64 + b
    int tid = threadIdx.x;      // 0..127
    if (tid < 64) sm[tid] = mask[tb * 64 + tid];
    __syncthreads();
    float acc = b_head[tid];
    for (int w = 0; w < 64; ++w) {
        uint32_t m = sm[w];     // uniform per block -> no divergence
        int base = w << 5;
        while (m) {
            int bit = __builtin_ctz(m);
            m &= m - 1;
            acc += w_head[(size_t)(base + bit) * DOUT + tid];
        }
    }
    logits[(size_t)tb * DOUT + tid] = acc;
}

__global__ __launch_bounds__(128) void k_readout(const float* __restrict__ logits,
                                                 float* __restrict__ readout) {
    int b = blockIdx.x, cidx = threadIdx.x;
    float s = 0.0f;
    for (int t = 0; t < TT; ++t)
        s += logits[(size_t)t * (BB * DOUT) + b * DOUT + cidx];
    readout[b * DOUT + cidx] = s * (1.0f / (float)TT);
}

__global__ void k_scalars(const uint32_t* __restrict__ cnts, float* __restrict__ out) {
    if (threadIdx.x == 0 && blockIdx.x == 0) {
        out[BB * DOUT + TT * BB * DOUT]     = (float)cnts[0] / (float)(TT * BB * RR);
        out[BB * DOUT + TT * BB * DOUT + 1] = (float)cnts[1] / (float)NTOT;
    }
}

extern "C" void kernel_launch(void* const* d_in, const int* in_sizes, int n_in,
                              void* d_out, int out_size, void* d_ws, size_t ws_size,
                              hipStream_t stream) {
    const float* x      = (const float*)d_in[0];
    const float* w_in   = (const float*)d_in[1];
    const float* b_in   = (const float*)d_in[2];
    float*       w_rec  = (float*)d_in[3];        // masked in place (restored each launch)
    const float* w_head = (const float*)d_in[4];
    const float* b_head = (const float*)d_in[5];
    float* out = (float*)d_out;

    float*    drive = (float*)d_ws;
    uint32_t* mask  = (uint32_t*)((char*)d_ws + 134217728u);
    uint32_t* ctr   = mask + (TT * BB * 64);
    uint32_t* hist  = ctr + (TT * BB);
    uint32_t* state = hist + 256;
    uint32_t* cnts  = state + 8;

    // zero ctr + hist + state + cnts
    k_init<<<64, 256, 0, stream>>>(ctr, TT * BB + 256 + 8 + 2);

    for (int p = 0; p < 4; ++p) {
        k_hist<<<1024, 256, 0, stream>>>(w_rec, hist, state, p);
        k_select<<<1, 256, 0, stream>>>(hist, state, p);
    }
    k_count<<<1024, 256, 0, stream>>>(w_rec, state, cnts);
    k_mask<<<1024, 256, 0, stream>>>(w_rec, state);

    k_drive<<<dim3(128, 16), 256, 0, stream>>>(x, w_in, b_in, drive);

    k_scan<<<256, 256, 0, stream>>>(w_rec, drive, mask, ctr, cnts);

    k_head<<<TT * BB, 128, 0, stream>>>(mask, w_head, b_head, out + BB * DOUT);
    k_readout<<<BB, 128, 0, stream>>>(out + BB * DOUT, out);
    k_scalars<<<1, 64, 0, stream>>>(cnts, out);
}